// Round 7
// baseline (165.737 us; speedup 1.0000x reference)
//
#include <hip/hip_runtime.h>

// DetectionLoss: NB=3, C=20, S=7, D=35, B=8192 -> 401408 cells, ~112 MB read.
// R7 = R6 + __launch_bounds__(64, 2). R6's WRITE_SIZE=112MB exposed scratch
// spill: bare launch_bounds(64) let the compiler target high occupancy and
// cap VGPRs at 88, spilling r[18] (72 VGPRs, live across compute) to scratch
// -> every input byte round-tripped through HBM scratch. (64,2) = 2 waves/EU
// = 8 waves/CU (the LDS cap anyway, 18.4 KB/block) raises the VGPR budget to
// ~256 -> no spill. Structure unchanged: contiguous dwordx4 loads to regs
// (the only pattern measured at 6.3 TB/s), reg->LDS transpose, loads of tile
// t+1 in flight across compute of tile t, zero barriers, persistent waves.

#define NBOX 3
#define NCLS 20
#define SDIM 7
#define DCH  35
#define TILE_F4 560            // float4 per tensor per 64-cell tile
#define FLAT_F4 (2 * TILE_F4)  // 1120
#define LDS_F4  1152           // + pad to 18*64, 18432 B -> 8 blocks/CU

__global__ __launch_bounds__(64, 2) void detloss_kernel(
    const float* __restrict__ out_g, const float* __restrict__ tgt_g,
    float* __restrict__ partials, int n_tiles, float inv_nB)
{
    __shared__ float4 s_buf[LDS_F4];    // [0,560)=out, [560,1120)=tgt, rest pad

    const int lane = threadIdx.x;       // one wave per block
    const int wid  = blockIdx.x;
    const int nwv  = gridDim.x;

    float4 r[18];
    float lane_sum = 0.0f;

    // ---- 18 contiguous dwordx4 loads (copy-kernel pattern) ----
    auto load_tile = [&](int tile) {
        const float4* go = (const float4*)out_g + (long long)tile * TILE_F4;
        const float4* gt = (const float4*)tgt_g + (long long)tile * TILE_F4;
        #pragma unroll
        for (int j = 0; j < 18; ++j) {
            int k = j * 64 + lane;
            k = (k > FLAT_F4 - 1) ? (FLAT_F4 - 1) : k;   // clamp pad lanes (j=17,lane>=32)
            r[j] = (k < TILE_F4) ? go[k] : gt[k - TILE_F4];
        }
    };

    auto store_tile = [&]() {           // compiler inserts per-register vmcnt(N)
        #pragma unroll
        for (int j = 0; j < 18; ++j) {
            int k = j * 64 + lane;
            k = (k > FLAT_F4 - 1) ? (FLAT_F4 - 1) : k;   // dup writes same value: benign
            s_buf[k] = r[j];
        }
    };

    auto compute = [&]() {
        const float* sf = (const float*)s_buf;
        const float* o  = sf + lane * DCH;                 // packed 140B cells
        const float* g  = sf + 4 * TILE_F4 + lane * DCH;   // tgt section

        const float tx  = g[0] / 7.0f, ty = g[1] / 7.0f;
        const float thw = 0.5f * g[2], thh = 0.5f * g[3];
        const float tx1 = tx - thw, ty1 = ty - thh;
        const float tx2 = tx + thw, ty2 = ty + thh;
        const float a2  = (tx2 - tx1) * (ty2 - ty1);

        const float conf_t = g[4];
        const float obj    = (conf_t == 1.0f) ? 1.0f : 0.0f;
        const float noobj  = (conf_t == 0.0f) ? 1.0f : 0.0f;

        float biou = -__builtin_inff();  // strict > => first-index-wins (matches argmax)
        float conf_sq = 0.0f;
        float bo0 = 0.f, bo1 = 0.f, bo2 = 0.f, bo3 = 0.f, bo4 = 0.f;
        float bg0 = 0.f, bg1 = 0.f, bg2 = 0.f, bg3 = 0.f;

        #pragma unroll
        for (int i = 0; i < NBOX; ++i) {
            const float px  = o[5*i]   / 7.0f;
            const float py  = o[5*i+1] / 7.0f;
            const float phw = 0.5f * o[5*i+2];
            const float phh = 0.5f * o[5*i+3];
            const float px1 = px - phw, py1 = py - phh;
            const float px2 = px + phw, py2 = py + phh;

            const float ltx = fmaxf(px1, tx1), lty = fmaxf(py1, ty1);
            const float rbx = fminf(px2, tx2), rby = fminf(py2, ty2);
            const float w = fmaxf(rbx - ltx, 0.0f);
            const float h = fmaxf(rby - lty, 0.0f);
            const float inter = w * h;
            const float a1 = (px2 - px1) * (py2 - py1);
            const float iou = inter / (a1 + a2 - inter);

            const bool better = iou > biou;
            biou = better ? iou      : biou;
            bo0  = better ? o[5*i]   : bo0;
            bo1  = better ? o[5*i+1] : bo1;
            bo2  = better ? o[5*i+2] : bo2;
            bo3  = better ? o[5*i+3] : bo3;
            bo4  = better ? o[5*i+4] : bo4;
            bg0  = better ? g[5*i]   : bg0;
            bg1  = better ? g[5*i+1] : bg1;
            bg2  = better ? g[5*i+2] : bg2;
            bg3  = better ? g[5*i+3] : bg3;

            const float dc = o[5*i+4] - g[5*i+4];
            conf_sq += dc * dc;
        }

        float loss = 0.5f * noobj * conf_sq;

        const float dx = bo0 - bg0;
        const float dy = bo1 - bg1;
        const float xyl = dx*dx + dy*dy;
        const float dw = sqrtf(bo2) - sqrtf(bg2);
        const float dh = sqrtf(bo3) - sqrtf(bg3);
        const float whl = dw*dw + dh*dh;
        const float dcf = bo4 - biou;
        const float contain = dcf * dcf;

        float cls = 0.0f;
        #pragma unroll
        for (int c = 0; c < NCLS; ++c) {
            const float d = o[5*NBOX + c] - g[5*NBOX + c];
            cls += d * d;
        }

        lane_sum += loss + obj * (5.0f * (xyl + whl) + contain + cls);
    };

    // ---- software pipeline: load(t+1) in flight across compute(t), no barriers ----
    if (wid < n_tiles) {
        load_tile(wid);
        store_tile();
        for (int nxt = wid + nwv; nxt < n_tiles; nxt += nwv) {
            load_tile(nxt);     // 18 loads in flight across compute below
            compute();          // reads LDS (in-order per wave vs writes after)
            store_tile();
        }
        compute();
    }

    // ---- wave reduce -> one partial per wave ----
    float v = lane_sum * inv_nB;
    #pragma unroll
    for (int off = 32; off > 0; off >>= 1)
        v += __shfl_down(v, off);
    if (lane == 0) partials[wid] = v;
}

__global__ __launch_bounds__(1024) void reduce_kernel(
    const float* __restrict__ partials, float* __restrict__ out, int n)
{
    __shared__ float s[1024 / 64];
    float v = 0.0f;
    for (int i = threadIdx.x; i < n; i += 1024) v += partials[i];
    #pragma unroll
    for (int off = 32; off > 0; off >>= 1)
        v += __shfl_down(v, off);
    if ((threadIdx.x & 63) == 0) s[threadIdx.x >> 6] = v;
    __syncthreads();
    if (threadIdx.x == 0) {
        float t = 0.0f;
        #pragma unroll
        for (int w = 0; w < 1024 / 64; ++w) t += s[w];
        out[0] = t;
    }
}

extern "C" void kernel_launch(void* const* d_in, const int* in_sizes, int n_in,
                              void* d_out, int out_size, void* d_ws, size_t ws_size,
                              hipStream_t stream) {
    const float* out_p = (const float*)d_in[0];
    const float* tgt_p = (const float*)d_in[1];
    float* res  = (float*)d_out;
    float* part = (float*)d_ws;

    const int n_cells = in_sizes[0] / DCH;            // 401408
    const int nB = n_cells / (SDIM * SDIM);           // 8192
    const float inv_nB = 1.0f / (float)nB;
    const int n_tiles = n_cells / 64;                 // 6272 (exact)

    const int nblocks = 2048;                         // 8 single-wave blocks/CU (LDS-capped)
    hipLaunchKernelGGL(detloss_kernel, dim3(nblocks), dim3(64), 0, stream,
                       out_p, tgt_p, part, n_tiles, inv_nB);
    hipLaunchKernelGGL(reduce_kernel, dim3(1), dim3(1024), 0, stream,
                       part, res, nblocks);
}

// Round 8
// 128.574 us; speedup vs baseline: 1.2890x; 1.2890x over previous
//
#include <hip/hip_runtime.h>

// DetectionLoss: NB=3, C=20, S=7, D=35, B=8192 -> 401408 cells, ~112 MB read.
// R8 = R6/R7 structure with the staging tile in 18 NAMED float4 registers.
// R6/R7 post-mortem: VGPR_Count=88 in BOTH rounds + WRITE_SIZE=112MB =>
// `float4 r[18]` was never SROA-promoted (lambda-captured array -> alloca in
// scratch), so the whole input round-tripped through scratch HBM regardless
// of launch_bounds. Named scalars cannot be demoted; macros give straight-
// line code. Otherwise unchanged: contiguous copy-shaped dwordx4 loads,
// reg->LDS transpose, tile t+1 loads in flight across compute(t), zero
// barriers, persistent single-wave blocks, 8 blocks/CU (LDS 17.9KB).

#define NBOX 3
#define NCLS 20
#define SDIM 7
#define DCH  35
#define TILE_F4 560            // float4 per tensor per 64-cell tile
#define FLAT_F4 (2 * TILE_F4)  // 1120

__global__ __launch_bounds__(64, 2) void detloss_kernel(
    const float* __restrict__ out_g, const float* __restrict__ tgt_g,
    float* __restrict__ partials, int n_tiles, float inv_nB)
{
    __shared__ float4 s_buf[FLAT_F4];   // 17920 B: [0,560)=out, [560,1120)=tgt

    const int lane = threadIdx.x;       // one wave per block
    const int wid  = blockIdx.x;
    const int nwv  = gridDim.x;

    const float4* go;
    const float4* gt;
    float4 r0, r1, r2, r3, r4, r5, r6, r7, r8, r9,
           r10, r11, r12, r13, r14, r15, r16, r17;
    float lane_sum = 0.0f;

#define LOADJ(RJ, J) do {                                            \
        int k_ = (J) * 64 + lane;                                    \
        if (k_ > FLAT_F4 - 1) k_ = FLAT_F4 - 1;                      \
        RJ = (k_ < TILE_F4) ? go[k_] : gt[k_ - TILE_F4];             \
    } while (0)

#define STOREJ(RJ, J) do {                                           \
        const int k_ = (J) * 64 + lane;                              \
        s_buf[k_] = RJ;                                              \
    } while (0)

#define LOAD_TILE(T) do {                                            \
        go = (const float4*)out_g + (long long)(T) * TILE_F4;        \
        gt = (const float4*)tgt_g + (long long)(T) * TILE_F4;        \
        LOADJ(r0,0);  LOADJ(r1,1);  LOADJ(r2,2);  LOADJ(r3,3);       \
        LOADJ(r4,4);  LOADJ(r5,5);  LOADJ(r6,6);  LOADJ(r7,7);       \
        LOADJ(r8,8);  LOADJ(r9,9);  LOADJ(r10,10); LOADJ(r11,11);    \
        LOADJ(r12,12); LOADJ(r13,13); LOADJ(r14,14); LOADJ(r15,15);  \
        LOADJ(r16,16); LOADJ(r17,17);                                \
    } while (0)

#define STORE_TILE() do {                                            \
        STOREJ(r0,0);  STOREJ(r1,1);  STOREJ(r2,2);  STOREJ(r3,3);   \
        STOREJ(r4,4);  STOREJ(r5,5);  STOREJ(r6,6);  STOREJ(r7,7);   \
        STOREJ(r8,8);  STOREJ(r9,9);  STOREJ(r10,10); STOREJ(r11,11);\
        STOREJ(r12,12); STOREJ(r13,13); STOREJ(r14,14); STOREJ(r15,15);\
        STOREJ(r16,16);                                              \
        if (lane < 32) STOREJ(r17,17);  /* j=17 valid only for lanes<32 */ \
    } while (0)

    auto compute = [&]() {
        const float* sf = (const float*)s_buf;
        const float* o  = sf + lane * DCH;                 // packed 140B cells
        const float* g  = sf + 4 * TILE_F4 + lane * DCH;   // tgt section

        const float tx  = g[0] / 7.0f, ty = g[1] / 7.0f;
        const float thw = 0.5f * g[2], thh = 0.5f * g[3];
        const float tx1 = tx - thw, ty1 = ty - thh;
        const float tx2 = tx + thw, ty2 = ty + thh;
        const float a2  = (tx2 - tx1) * (ty2 - ty1);

        const float conf_t = g[4];
        const float obj    = (conf_t == 1.0f) ? 1.0f : 0.0f;
        const float noobj  = (conf_t == 0.0f) ? 1.0f : 0.0f;

        float biou = -__builtin_inff();  // strict > => first-index-wins (matches argmax)
        float conf_sq = 0.0f;
        float bo0 = 0.f, bo1 = 0.f, bo2 = 0.f, bo3 = 0.f, bo4 = 0.f;
        float bg0 = 0.f, bg1 = 0.f, bg2 = 0.f, bg3 = 0.f;

        #pragma unroll
        for (int i = 0; i < NBOX; ++i) {
            const float px  = o[5*i]   / 7.0f;
            const float py  = o[5*i+1] / 7.0f;
            const float phw = 0.5f * o[5*i+2];
            const float phh = 0.5f * o[5*i+3];
            const float px1 = px - phw, py1 = py - phh;
            const float px2 = px + phw, py2 = py + phh;

            const float ltx = fmaxf(px1, tx1), lty = fmaxf(py1, ty1);
            const float rbx = fminf(px2, tx2), rby = fminf(py2, ty2);
            const float w = fmaxf(rbx - ltx, 0.0f);
            const float h = fmaxf(rby - lty, 0.0f);
            const float inter = w * h;
            const float a1 = (px2 - px1) * (py2 - py1);
            const float iou = inter / (a1 + a2 - inter);

            const bool better = iou > biou;
            biou = better ? iou      : biou;
            bo0  = better ? o[5*i]   : bo0;
            bo1  = better ? o[5*i+1] : bo1;
            bo2  = better ? o[5*i+2] : bo2;
            bo3  = better ? o[5*i+3] : bo3;
            bo4  = better ? o[5*i+4] : bo4;
            bg0  = better ? g[5*i]   : bg0;
            bg1  = better ? g[5*i+1] : bg1;
            bg2  = better ? g[5*i+2] : bg2;
            bg3  = better ? g[5*i+3] : bg3;

            const float dc = o[5*i+4] - g[5*i+4];
            conf_sq += dc * dc;
        }

        float loss = 0.5f * noobj * conf_sq;

        const float dx = bo0 - bg0;
        const float dy = bo1 - bg1;
        const float xyl = dx*dx + dy*dy;
        const float dw = sqrtf(bo2) - sqrtf(bg2);
        const float dh = sqrtf(bo3) - sqrtf(bg3);
        const float whl = dw*dw + dh*dh;
        const float dcf = bo4 - biou;
        const float contain = dcf * dcf;

        float cls = 0.0f;
        #pragma unroll
        for (int c = 0; c < NCLS; ++c) {
            const float d = o[5*NBOX + c] - g[5*NBOX + c];
            cls += d * d;
        }

        lane_sum += loss + obj * (5.0f * (xyl + whl) + contain + cls);
    };

    // ---- software pipeline: load(t+1) in flight across compute(t), no barriers ----
    if (wid < n_tiles) {
        LOAD_TILE(wid);
        STORE_TILE();
        for (int nxt = wid + nwv; nxt < n_tiles; nxt += nwv) {
            LOAD_TILE(nxt);     // 18 loads in flight across compute below
            compute();          // reads LDS (in-order per wave vs writes after)
            STORE_TILE();
        }
        compute();
    }

    // ---- wave reduce -> one partial per wave ----
    float v = lane_sum * inv_nB;
    #pragma unroll
    for (int off = 32; off > 0; off >>= 1)
        v += __shfl_down(v, off);
    if (lane == 0) partials[wid] = v;
}

__global__ __launch_bounds__(1024) void reduce_kernel(
    const float* __restrict__ partials, float* __restrict__ out, int n)
{
    __shared__ float s[1024 / 64];
    float v = 0.0f;
    for (int i = threadIdx.x; i < n; i += 1024) v += partials[i];
    #pragma unroll
    for (int off = 32; off > 0; off >>= 1)
        v += __shfl_down(v, off);
    if ((threadIdx.x & 63) == 0) s[threadIdx.x >> 6] = v;
    __syncthreads();
    if (threadIdx.x == 0) {
        float t = 0.0f;
        #pragma unroll
        for (int w = 0; w < 1024 / 64; ++w) t += s[w];
        out[0] = t;
    }
}

extern "C" void kernel_launch(void* const* d_in, const int* in_sizes, int n_in,
                              void* d_out, int out_size, void* d_ws, size_t ws_size,
                              hipStream_t stream) {
    const float* out_p = (const float*)d_in[0];
    const float* tgt_p = (const float*)d_in[1];
    float* res  = (float*)d_out;
    float* part = (float*)d_ws;

    const int n_cells = in_sizes[0] / DCH;            // 401408
    const int nB = n_cells / (SDIM * SDIM);           // 8192
    const float inv_nB = 1.0f / (float)nB;
    const int n_tiles = n_cells / 64;                 // 6272 (exact)

    const int nblocks = 2048;                         // 8 single-wave blocks/CU (LDS-capped)
    hipLaunchKernelGGL(detloss_kernel, dim3(nblocks), dim3(64), 0, stream,
                       out_p, tgt_p, part, n_tiles, inv_nB);
    hipLaunchKernelGGL(reduce_kernel, dim3(1), dim3(1024), 0, stream,
                       part, res, nblocks);
}